// Round 5
// baseline (388.243 us; speedup 1.0000x reference)
//
#include <hip/hip_runtime.h>

// Problem constants (MultiScaleRetention: B=4, L=4096, D=1024, H=16, DH=64)
#define BB 4
#define LL 4096
#define DM 1024
#define NH 16
#define MM (BB * LL)   // 16384 rows
#define CC2 256        // scan chunks per sequence
#define LC2 16         // chunk length (CC2*LC2 == LL)

typedef unsigned short u16;
typedef float f32x16 __attribute__((ext_vector_type(16)));
typedef __bf16 mfma_in __attribute__((ext_vector_type(8)));

__device__ __forceinline__ u16 f2bf(float f) {
    unsigned u = __float_as_uint(f);
    u += 0x7FFFu + ((u >> 16) & 1u);   // RNE
    return (u16)(u >> 16);
}
__device__ __forceinline__ float bf2f(u16 u) {
    return __uint_as_float(((unsigned)u) << 16);
}

// async global->LDS, 16B per lane; LDS dest = wave-uniform base + lane*16
__device__ __forceinline__ void gld_lds16(const u16* g, u16* l) {
    __builtin_amdgcn_global_load_lds(
        (const __attribute__((address_space(1))) void*)g,
        (__attribute__((address_space(3))) void*)l,
        16, 0, 0);
}

// ---------------------------------------------------------------- conversions
#define XF4 (MM * DM / 4)
#define WF4 (DM * DM / 4)
__global__ __launch_bounds__(256)
void cvt_all(const float* __restrict__ x,
             const float* __restrict__ w0, const float* __restrict__ w1,
             const float* __restrict__ w2, const float* __restrict__ w3,
             u16* __restrict__ dst) {
    int i = blockIdx.x * 256 + threadIdx.x;
    const float* src;
    int si;
    if (i < XF4) { src = x; si = i; }
    else {
        int j = i - XF4;
        const float* ws[4] = {w0, w1, w2, w3};
        src = ws[j >> 18];
        si = j & (WF4 - 1);
    }
    float4 f = ((const float4*)src)[si];
    ushort4 o;
    o.x = f2bf(f.x); o.y = f2bf(f.y); o.z = f2bf(f.z); o.w = f2bf(f.w);
    ((ushort4*)dst)[i] = o;
}

// ---------------------------------------------------------------- GEMM main loop
// BK=64 (As/Bs 16KiB each), XOR bank swizzle (R4-verified, 0 conflicts):
// LDS row = 64 u16 (8 chunks of 16B); chunk (row, logical c) stored at phys c^(row&7).
// MFMA: 32x32x16 bf16, wave tile 64x64 = 2x2 tiles.
// A-frag: row = lane&31, k = (lane>>5)*8 + j  -> logical chunk s*2 + (lane>>5)
// C/D  : col = lane&31, row = (reg&3) + 8*(reg>>2) + 4*(lane>>5)   [m74/m101]
__device__ __forceinline__ void mainloop32(
    const u16* __restrict__ A, const u16* __restrict__ B, int K,
    int mBlk, int nBlk, u16* As, u16* Bs, f32x16 acc[2][2]) {
    const int tid  = threadIdx.x;
    const int wave = tid >> 6;
    const int lane = tid & 63;
    const int l32  = lane & 31;
    const int half = lane >> 5;
    const int wm   = (wave >> 1) * 64;
    const int wn   = (wave & 1) * 64;

    const int srow8 = wave * 8 + (lane >> 3);
    const int cOff  = ((lane & 7) ^ (lane >> 3)) * 8;

    const u16* gA[4];
    const u16* gB[4];
    u16* lA[4];
    u16* lB[4];
#pragma unroll
    for (int j = 0; j < 4; j++) {
        gA[j] = A + (size_t)(mBlk + j * 32 + srow8) * K + cOff;
        gB[j] = B + (size_t)(nBlk + j * 32 + srow8) * K + cOff;
        lA[j] = As + (j * 32 + wave * 8) * 64;
        lB[j] = Bs + (j * 32 + wave * 8) * 64;
    }

    // fragment LDS row offsets (row*64) and per-step phys chunk offsets
    int rowA[2], rowB[2];
#pragma unroll
    for (int i = 0; i < 2; i++) {
        rowA[i] = (wm + i * 32 + l32) * 64;
        rowB[i] = (wn + i * 32 + l32) * 64;
    }
    int cs[4];
#pragma unroll
    for (int s = 0; s < 4; s++)
        cs[s] = ((s * 2 + half) ^ (lane & 7)) * 8;

    for (int kt = 0; kt < K; kt += 64) {
        __syncthreads();   // protect previous iteration's LDS reads
#pragma unroll
        for (int j = 0; j < 4; j++) gld_lds16(gA[j] + kt, lA[j]);
#pragma unroll
        for (int j = 0; j < 4; j++) gld_lds16(gB[j] + kt, lB[j]);
        __syncthreads();   // drains vmcnt -> staged data visible

#pragma unroll
        for (int s = 0; s < 4; s++) {
            mfma_in af[2], bfr[2];
#pragma unroll
            for (int i = 0; i < 2; i++)
                af[i] = *(const mfma_in*)&As[rowA[i] + cs[s]];
#pragma unroll
            for (int j = 0; j < 2; j++)
                bfr[j] = *(const mfma_in*)&Bs[rowB[j] + cs[s]];
#pragma unroll
            for (int i = 0; i < 2; i++)
#pragma unroll
                for (int j = 0; j < 2; j++)
                    acc[i][j] = __builtin_amdgcn_mfma_f32_32x32x16_bf16(af[i], bfr[j], acc[i][j], 0, 0, 0);
        }
    }
}

// fused q/v/g projection: B = concatenated 3072x1024 weights; 3 bf16 outputs
__global__ __launch_bounds__(256)
void gemm_qvg(const u16* __restrict__ A, const u16* __restrict__ B,
              u16* __restrict__ oq, u16* __restrict__ ov, u16* __restrict__ og,
              int K) {
    __shared__ u16 As[128 * 64];
    __shared__ u16 Bs[128 * 64];
    const int mBlk = blockIdx.x * 128;
    const int nBlk = blockIdx.y * 128;

    f32x16 acc[2][2] = {};
    mainloop32(A, B, K, mBlk, nBlk, As, Bs, acc);

    const int tid  = threadIdx.x;
    const int wave = tid >> 6;
    const int lane = tid & 63;
    const int l32  = lane & 31;
    const int half = lane >> 5;
    const int wm   = (wave >> 1) * 64;
    const int wn   = (wave & 1) * 64;

    u16* outs[3] = {oq, ov, og};
    u16* O = outs[nBlk >> 10];
    const int nIn = nBlk & 1023;
#pragma unroll
    for (int i = 0; i < 2; i++) {
#pragma unroll
        for (int j = 0; j < 2; j++) {
            int col = nIn + wn + j * 32 + l32;
#pragma unroll
            for (int r = 0; r < 16; r++) {
                int row = mBlk + wm + i * 32 + (r & 3) + 8 * (r >> 2) + 4 * half;
                O[(size_t)row * DM + col] = f2bf(acc[i][j][r]);
            }
        }
    }
}

// output projection: C (f32) = A @ B^T
__global__ __launch_bounds__(256)
void gemm_out(const u16* __restrict__ A, const u16* __restrict__ B,
              float* __restrict__ C, int N, int K) {
    __shared__ u16 As[128 * 64];
    __shared__ u16 Bs[128 * 64];
    const int mBlk = blockIdx.x * 128;
    const int nBlk = blockIdx.y * 128;

    f32x16 acc[2][2] = {};
    mainloop32(A, B, K, mBlk, nBlk, As, Bs, acc);

    const int tid  = threadIdx.x;
    const int wave = tid >> 6;
    const int lane = tid & 63;
    const int l32  = lane & 31;
    const int half = lane >> 5;
    const int wm   = (wave >> 1) * 64;
    const int wn   = (wave & 1) * 64;

#pragma unroll
    for (int i = 0; i < 2; i++) {
#pragma unroll
        for (int j = 0; j < 2; j++) {
            int col = nBlk + wn + j * 32 + l32;
#pragma unroll
            for (int r = 0; r < 16; r++) {
                int row = mBlk + wm + i * 32 + (r & 3) + 8 * (r >> 2) + 4 * half;
                C[(size_t)row * N + col] = acc[i][j][r];
            }
        }
    }
}

// ---------------------------------------------------------------- scan phase A:
// local (seed=0) scan per chunk of 16, store chunk-end value.
__global__ __launch_bounds__(256)
void scan_ends(const u16* __restrict__ v, const float* __restrict__ beta,
               float* __restrict__ ebuf) {
    int d = blockIdx.x * 256 + threadIdx.x;
    int c = blockIdx.y, b = blockIdx.z;
    int h = d >> 6;
    float lam = 1.0f / (1.0f + __expf(-beta[h]));
    size_t idx = ((size_t)b * LL + (size_t)c * LC2) * DM + d;
    float s = 0.0f;
#pragma unroll
    for (int i = 0; i < LC2; i++) {
        s = lam * s + bf2f(v[idx]);
        idx += DM;
    }
    ebuf[((size_t)b * CC2 + c) * DM + d] = s;
}

// ---------------------------------------------------------------- scan phase B+C fused:
// carry computed in-block from ebuf (4MB, L2-resident), then seeded re-scan +
// y=q*state + LayerNorm + SiLU gate -> bf16.
__global__ __launch_bounds__(256)
void scan_ln_gate(const u16* __restrict__ v, const u16* __restrict__ q,
                  const u16* __restrict__ g, const float* __restrict__ ebuf,
                  const float* __restrict__ beta, const float* __restrict__ gamma,
                  const float* __restrict__ lnb, u16* __restrict__ out) {
    __shared__ float red[2][8];
    const int t = threadIdx.x;
    const int c = blockIdx.x, b = blockIdx.y;
    const int wave = t >> 6, lane = t & 63;
    const int d0 = t * 4;
    const int h = d0 >> 6;
    float lam = 1.0f / (1.0f + __expf(-beta[h]));
    float lamC = lam;
#pragma unroll
    for (int i = 0; i < 4; i++) lamC *= lamC;  // lam^16

    // carry entering chunk c: s = sum_{j<c} lamC^(c-1-j) * ebuf[b][j][:]
    float s0 = 0.f, s1 = 0.f, s2 = 0.f, s3 = 0.f;
    {
        const float4* e4 = (const float4*)(ebuf + (size_t)b * CC2 * DM + d0);
        for (int j = 0; j < c; j++) {
            float4 e = e4[(size_t)j * (DM / 4)];
            s0 = lamC * s0 + e.x;
            s1 = lamC * s1 + e.y;
            s2 = lamC * s2 + e.z;
            s3 = lamC * s3 + e.w;
        }
    }

    float4 gm = ((const float4*)gamma)[t];
    float4 bt = ((const float4*)lnb)[t];
    size_t base = ((size_t)b * LL + (size_t)c * LC2) * DM + d0;

    for (int i = 0; i < LC2; i++) {
        ushort4 v4 = *(const ushort4*)(v + base);
        ushort4 q4 = *(const ushort4*)(q + base);
        ushort4 g4 = *(const ushort4*)(g + base);
        s0 = lam * s0 + bf2f(v4.x);
        s1 = lam * s1 + bf2f(v4.y);
        s2 = lam * s2 + bf2f(v4.z);
        s3 = lam * s3 + bf2f(v4.w);
        float y0 = bf2f(q4.x) * s0, y1 = bf2f(q4.y) * s1;
        float y2 = bf2f(q4.z) * s2, y3 = bf2f(q4.w) * s3;
        float sum = y0 + y1 + y2 + y3;
        float sq  = y0 * y0 + y1 * y1 + y2 * y2 + y3 * y3;
#pragma unroll
        for (int off = 32; off > 0; off >>= 1) {
            sum += __shfl_xor(sum, off);
            sq  += __shfl_xor(sq, off);
        }
        int p = i & 1;
        if (lane == 0) { red[p][wave] = sum; red[p][4 + wave] = sq; }
        __syncthreads();
        float ts = red[p][0] + red[p][1] + red[p][2] + red[p][3];
        float tq = red[p][4] + red[p][5] + red[p][6] + red[p][7];
        float mu  = ts * (1.0f / DM);
        float inv = rsqrtf(tq * (1.0f / DM) - mu * mu + 1e-5f);

        float gv0 = bf2f(g4.x), gv1 = bf2f(g4.y), gv2 = bf2f(g4.z), gv3 = bf2f(g4.w);
        float x0 = ((y0 - mu) * inv * gm.x + bt.x) * (gv0 / (1.0f + __expf(-gv0)));
        float x1 = ((y1 - mu) * inv * gm.y + bt.y) * (gv1 / (1.0f + __expf(-gv1)));
        float x2 = ((y2 - mu) * inv * gm.z + bt.z) * (gv2 / (1.0f + __expf(-gv2)));
        float x3 = ((y3 - mu) * inv * gm.w + bt.w) * (gv3 / (1.0f + __expf(-gv3)));
        ushort4 o;
        o.x = f2bf(x0); o.y = f2bf(x1); o.z = f2bf(x2); o.w = f2bf(x3);
        *(ushort4*)(out + base) = o;
        base += DM;
    }
}

// ---------------------------------------------------------------- launcher
extern "C" void kernel_launch(void* const* d_in, const int* in_sizes, int n_in,
                              void* d_out, int out_size, void* d_ws, size_t ws_size,
                              hipStream_t stream) {
    const float* x     = (const float*)d_in[0];
    const float* Wq    = (const float*)d_in[1];
    const float* Wv    = (const float*)d_in[2];
    const float* Wg    = (const float*)d_in[3];
    const float* Wo    = (const float*)d_in[4];
    const float* beta  = (const float*)d_in[5];
    const float* gamma = (const float*)d_in[6];
    const float* lnb   = (const float*)d_in[7];

    // workspace layout (bf16 elements) — xb..Wob contiguous for cvt_all
    u16* xb  = (u16*)d_ws;                    // reused as y_final
    u16* Wqb = xb + (size_t)MM * DM;          // Wq,Wv,Wg concat = 3072x1024
    u16* Wob = Wqb + (size_t)3 * DM * DM;
    u16* qb  = Wob + (size_t)DM * DM;
    u16* vb  = qb + (size_t)MM * DM;
    u16* gb  = vb + (size_t)MM * DM;
    float* ebuf = (float*)(gb + (size_t)MM * DM);   // BB*CC2*DM f32
    u16* yfin = xb;

    // 1) fp32 -> bf16, single launch
    cvt_all<<<(XF4 + 4 * WF4 + 255) / 256, 256, 0, stream>>>(x, Wq, Wv, Wg, Wo, xb);

    // 2) fused q/v/g projection (N=3072 concat)
    dim3 gq(MM / 128, 3 * DM / 128);
    gemm_qvg<<<gq, 256, 0, stream>>>(xb, Wqb, qb, vb, gb, DM);

    // 3) retention scan: chunk ends, then fused carry+rescan+LN+gate
    dim3 gs(DM / 256, CC2, BB);
    scan_ends<<<gs, 256, 0, stream>>>(vb, beta, ebuf);
    dim3 gf(CC2, BB);
    scan_ln_gate<<<gf, 256, 0, stream>>>(vb, qb, gb, ebuf, beta, gamma, lnb, yfin);

    // 4) output projection (fp32 out)
    dim3 go(MM / 128, DM / 128);
    gemm_out<<<go, 256, 0, stream>>>(yfin, Wob, (float*)d_out, DM, DM);
}